// Round 2
// 748.942 us; speedup vs baseline: 1.0056x; 1.0056x over previous
//
#include <hip/hip_runtime.h>

// RRGCN cell update (reference collapses to elementwise LSTM-ish math):
//   S     = X + H
//   g     = sigmoid(S)        (I == F == O, identical math in reference)
//   T     = tanh(S)
//   C_new = g*C + g*T = g*(C + T)
//   H_new = g * tanh(C_new)
// edge_attr / global_attr are dead inputs (identity conv in the source).
// Memory-bound: 3 reads + 2 writes of 204.8 MB fp32 => ~1.02 GB @ ~6.3 TB/s
// => ~163 us kernel-time roofline.
//
// V3 = V2 with native clang vector type (__builtin_nontemporal_* requires
// ext_vector_type, not HIP's float4 class):
//  - UNROLL=4 per thread, all 12 global_load_dwordx4 issued before compute
//    (4x memory-level parallelism per wave; 12500 blocks instead of 50000).
//  - nontemporal loads AND stores (pure streaming kernel, no reuse).

#define UNROLL 4

typedef float f4 __attribute__((ext_vector_type(4)));

__device__ __forceinline__ float sigm_fast(float x) {
    return 1.0f / (1.0f + __expf(-x));
}

// Overflow-safe fast tanh: exp(-2|x|) in (0,1], no inf/NaN for any input.
__device__ __forceinline__ float tanh_fast(float x) {
    float e = __expf(-2.0f * fabsf(x));
    float t = (1.0f - e) / (1.0f + e);
    return copysignf(t, x);
}

__device__ __forceinline__ void rrgcn_comp4(const f4& x, const f4& h,
                                            const f4& c, f4& hn, f4& cn) {
#pragma unroll
    for (int j = 0; j < 4; ++j) {
        float s  = x[j] + h[j];
        float g  = sigm_fast(s);
        float t  = tanh_fast(s);
        float cv = g * (c[j] + t);
        cn[j] = cv;
        hn[j] = g * tanh_fast(cv);
    }
}

__global__ __launch_bounds__(256) void rrgcn_cell_kernel(
    const f4* __restrict__ X,
    const f4* __restrict__ H,
    const f4* __restrict__ C,
    f4* __restrict__ Hn,
    f4* __restrict__ Cn,
    int n4)
{
    const int nth = gridDim.x * blockDim.x;           // threads in grid
    const int i0  = blockIdx.x * blockDim.x + threadIdx.x;

    if (i0 + (UNROLL - 1) * nth < n4) {
        // Main path (exact when n4 % (nth*UNROLL) == 0, which holds here:
        // 12.8e6 / (12500*256) = 4). All loads issued before any compute so
        // the wave has 12 independent dwordx4 loads in flight.
        f4 x[UNROLL], h[UNROLL], c[UNROLL];
#pragma unroll
        for (int k = 0; k < UNROLL; ++k)
            x[k] = __builtin_nontemporal_load(&X[i0 + k * nth]);
#pragma unroll
        for (int k = 0; k < UNROLL; ++k)
            h[k] = __builtin_nontemporal_load(&H[i0 + k * nth]);
#pragma unroll
        for (int k = 0; k < UNROLL; ++k)
            c[k] = __builtin_nontemporal_load(&C[i0 + k * nth]);

#pragma unroll
        for (int k = 0; k < UNROLL; ++k) {
            f4 hn, cn;
            rrgcn_comp4(x[k], h[k], c[k], hn, cn);
            const int idx = i0 + k * nth;
            __builtin_nontemporal_store(hn, &Hn[idx]);
            __builtin_nontemporal_store(cn, &Cn[idx]);
        }
    } else {
        // Tail path (robustness only; unused for the bench shape).
        for (int k = 0; k < UNROLL; ++k) {
            const int idx = i0 + k * nth;
            if (idx < n4) {
                f4 hn, cn;
                f4 x = __builtin_nontemporal_load(&X[idx]);
                f4 h = __builtin_nontemporal_load(&H[idx]);
                f4 c = __builtin_nontemporal_load(&C[idx]);
                rrgcn_comp4(x, h, c, hn, cn);
                __builtin_nontemporal_store(hn, &Hn[idx]);
                __builtin_nontemporal_store(cn, &Cn[idx]);
            }
        }
    }
}

extern "C" void kernel_launch(void* const* d_in, const int* in_sizes, int n_in,
                              void* d_out, int out_size, void* d_ws, size_t ws_size,
                              hipStream_t stream) {
    // setup_inputs order: X, edge_attr, global_attr, H, C  (all fp32)
    const float* X = (const float*)d_in[0];
    // d_in[1] = edge_attr (8x64)  -- unused (identity conv)
    // d_in[2] = global_attr (1x8) -- unused
    const float* H = (const float*)d_in[3];
    const float* C = (const float*)d_in[4];

    int n = in_sizes[0];              // 200000 * 256 = 51,200,000 (divisible by 4)
    int n4 = n / 4;

    float* out = (float*)d_out;       // [H_new (n) | C_new (n)]
    float* Hn = out;
    float* Cn = out + n;

    int block = 256;
    int per_block = block * UNROLL;
    int grid = (n4 + per_block - 1) / per_block;   // 12500 blocks
    rrgcn_cell_kernel<<<grid, block, 0, stream>>>(
        (const f4*)X, (const f4*)H, (const f4*)C,
        (f4*)Hn, (f4*)Cn, n4);
}